// Round 3
// baseline (356.724 us; speedup 1.0000x reference)
//
#include <hip/hip_runtime.h>
#include <math.h>

typedef __bf16 bf16_t;
typedef __bf16 bf16x8 __attribute__((ext_vector_type(8)));
typedef float f32x4 __attribute__((ext_vector_type(4)));

// async global->LDS, 16B per lane. Dest must be wave-uniform base; HW adds lane*16.
__device__ __forceinline__ void gload_lds16(const bf16_t* g, bf16_t* l) {
    __builtin_amdgcn_global_load_lds((const __attribute__((address_space(1))) void*)g,
                                     (__attribute__((address_space(3))) void*)l, 16, 0, 0);
}

// ---------------------------------------------------------------------------
// fp32 -> bf16 convert (vectorized 8/thread)
// ---------------------------------------------------------------------------
__global__ __launch_bounds__(256) void cvt_f32_to_bf16(const float* __restrict__ in,
                                                       bf16_t* __restrict__ out, int n8) {
    int i = blockIdx.x * 256 + threadIdx.x;
    if (i >= n8) return;
    const float4* p = (const float4*)in + (size_t)i * 2;
    float4 a = p[0], b = p[1];
    union { bf16_t h[8]; uint4 u; } pk;
    pk.h[0] = (bf16_t)a.x; pk.h[1] = (bf16_t)a.y; pk.h[2] = (bf16_t)a.z; pk.h[3] = (bf16_t)a.w;
    pk.h[4] = (bf16_t)b.x; pk.h[5] = (bf16_t)b.y; pk.h[6] = (bf16_t)b.z; pk.h[7] = (bf16_t)b.w;
    ((uint4*)out)[i] = pk.u;
}

// ---------------------------------------------------------------------------
// GEMM: C[M,N] = A[M,K] @ B[N,K]^T (+bias). 256x128 tile, BK=64, 512 thr =
// 8 waves (4 Mx2 N), per-wave 64x64. 4-phase/K-tile schedule (T3+T4):
// per phase {swizzled ds_read x8 || stage-issue -> barrier -> lgkmcnt(0) ->
// setprio(1) 8xMFMA setprio(0) -> barrier}; one counted vmcnt wait per tile.
// LDS XOR-swizzle chunk^=(row&7): conflict-free b128 reads; staged via
// pre-swizzled GLOBAL source + linear LDS dest (rule #21 both-sides).
// ---------------------------------------------------------------------------
template <typename OutT>
__device__ __forceinline__ void gemm_core(const bf16_t* __restrict__ A,
                                          const bf16_t* __restrict__ Bm,
                                          const float* __restrict__ bias,
                                          OutT* __restrict__ C, int M, int N, int K,
                                          int bx, int by) {
    __shared__ __align__(16) bf16_t As[2][256 * 64];
    __shared__ __align__(16) bf16_t Bs[2][128 * 64];
    const int tid = threadIdx.x;
    const int w = tid >> 6, l = tid & 63;
    const int l16 = l & 15, lg = l >> 4;
    const int wr = w >> 1, wc = w & 1;   // 4x2 wave grid
    const int m0 = bx * 256, n0 = by * 128;
    const int lsw = l16 & 7;

    f32x4 acc[4][4] = {};

    // stage one 128-row half of A (2 gload/thread), or the whole B (2 gload/thread).
    auto stageA = [&](int k0, int buf, int half) {
#pragma unroll
        for (int j = 0; j < 2; ++j) {
            int c = tid + (half * 2 + j) * 512;          // chunk id 0..2047
            int row = c >> 3;
            int kc = (c & 7) ^ (row & 7);                // pre-swizzled source
            gload_lds16(A + (size_t)(m0 + row) * K + k0 + kc * 8,
                        &As[buf][(w * 64 + (half * 2 + j) * 512) * 8]);
        }
    };
    auto stageB = [&](int k0, int buf) {
#pragma unroll
        for (int j = 0; j < 2; ++j) {
            int c = tid + j * 512;                       // chunk id 0..1023
            int row = c >> 3;
            int kc = (c & 7) ^ (row & 7);
            gload_lds16(Bm + (size_t)(n0 + row) * K + k0 + kc * 8,
                        &Bs[buf][(w * 64 + j * 512) * 8]);
        }
    };

    stageA(0, 0, 0); stageA(0, 0, 1); stageB(0, 0);
    asm volatile("s_waitcnt vmcnt(0)" ::: "memory");
    __builtin_amdgcn_s_barrier();

    const int nt = K / 64;
    for (int t = 0; t < nt; ++t) {
        const int cur = t & 1;
        const int k1 = (t + 1) * 64;
        const bool pf = (t + 1 < nt);
#pragma unroll
        for (int p = 0; p < 4; ++p) {
            const int mh = p >> 1, nh = p & 1;           // quadrant of per-wave 64x64
            bf16x8 af[2][2], bfr[2][2];                  // [frag][kstep]
#pragma unroll
            for (int i = 0; i < 2; ++i)
#pragma unroll
                for (int ks = 0; ks < 2; ++ks) {
                    int arow = wr * 64 + (mh * 2 + i) * 16 + l16;
                    af[i][ks] = *(const bf16x8*)&As[cur][arow * 64 + (((ks << 2) | lg) ^ lsw) * 8];
                    int brow = wc * 64 + (nh * 2 + i) * 16 + l16;
                    bfr[i][ks] = *(const bf16x8*)&Bs[cur][brow * 64 + (((ks << 2) | lg) ^ lsw) * 8];
                }
            if (pf) {
                if (p == 0) { stageA(k1, cur ^ 1, 0); stageA(k1, cur ^ 1, 1); }
                else if (p == 1) { stageB(k1, cur ^ 1); }
            }
            __builtin_amdgcn_s_barrier();
            asm volatile("s_waitcnt lgkmcnt(0)" ::: "memory");
            __builtin_amdgcn_sched_barrier(0);           // rule #18: pin MFMA below wait
            __builtin_amdgcn_s_setprio(1);
#pragma unroll
            for (int ks = 0; ks < 2; ++ks)
#pragma unroll
                for (int i = 0; i < 2; ++i)
#pragma unroll
                    for (int jn = 0; jn < 2; ++jn)
                        acc[mh * 2 + i][nh * 2 + jn] = __builtin_amdgcn_mfma_f32_16x16x32_bf16(
                            af[i][ks], bfr[jn][ks], acc[mh * 2 + i][nh * 2 + jn], 0, 0, 0);
            __builtin_amdgcn_s_setprio(0);
            if (p == 3) asm volatile("s_waitcnt vmcnt(0)" ::: "memory");  // next tile staged
            __builtin_amdgcn_s_barrier();
        }
    }
    // epilogue: C/D layout row=lg*4+r, col=l16
#pragma unroll
    for (int mf = 0; mf < 4; ++mf)
#pragma unroll
        for (int nf = 0; nf < 4; ++nf) {
            int col = n0 + wc * 64 + nf * 16 + l16;
            float bv = bias ? bias[col] : 0.f;
#pragma unroll
            for (int r = 0; r < 4; ++r) {
                int row = m0 + wr * 64 + mf * 16 + lg * 4 + r;
                C[(size_t)row * N + col] = (OutT)(acc[mf][nf][r] + bv);
            }
        }
}

// qkv: grid flat 768 blocks (16 x-tiles, 16 y-tiles, 3 mats), XCD-swizzled.
__global__ __launch_bounds__(512, 2) void gemm_qkv(const bf16_t* __restrict__ A,
                                                   const bf16_t* __restrict__ W0,
                                                   const bf16_t* __restrict__ W1,
                                                   const bf16_t* __restrict__ W2,
                                                   bf16_t* __restrict__ O0, bf16_t* __restrict__ O1,
                                                   bf16_t* __restrict__ O2, int M, int N, int K) {
    int flat = blockIdx.x + 16 * (blockIdx.y + 16 * blockIdx.z);
    int idx = (flat & 7) * 96 + (flat >> 3);   // bijective: 768 % 8 == 0
    int bx = idx & 15, by = (idx >> 4) & 15, bz = idx >> 8;
    const bf16_t* Bm = (bz == 0) ? W0 : (bz == 1) ? W1 : W2;
    bf16_t* Cp = (bz == 0) ? O0 : (bz == 1) ? O1 : O2;
    gemm_core<bf16_t>(A, Bm, nullptr, Cp, M, N, K, bx, by);
}

__global__ __launch_bounds__(512, 2) void gemm_bias_f32(const bf16_t* __restrict__ A,
                                                        const bf16_t* __restrict__ Bm,
                                                        const float* __restrict__ bias,
                                                        float* __restrict__ C, int M, int N, int K) {
    int flat = blockIdx.x + 16 * blockIdx.y;
    int idx = (flat & 7) * 32 + (flat >> 3);   // 256 % 8 == 0
    int bx = idx & 15, by = idx >> 4;
    gemm_core<float>(A, Bm, bias, C, M, N, K, bx, by);
}

// ---------------------------------------------------------------------------
// V transpose: [B*S, D] -> [B, H, 128, S]  (64x64 LDS tiles)
// ---------------------------------------------------------------------------
__global__ __launch_bounds__(256) void transpose_v(const bf16_t* __restrict__ V,
                                                   bf16_t* __restrict__ Vt, int S, int H, int Bn) {
    __shared__ bf16_t t[64][72];
    const int s0 = blockIdx.x * 64, d0 = blockIdx.y * 64, b = blockIdx.z;
    const int D = H * 128;
    const int tid = threadIdx.x;
#pragma unroll
    for (int j = 0; j < 2; ++j) {
        int chunk = tid + j * 256;
        int r = chunk >> 3, c8 = chunk & 7;
        *(uint4*)&t[r][c8 * 8] = *(const uint4*)(V + (size_t)(b * S + s0 + r) * D + d0 + c8 * 8);
    }
    __syncthreads();
#pragma unroll
    for (int j = 0; j < 2; ++j) {
        int chunk = tid + j * 256;
        int rr = chunk >> 3, cc = chunk & 7;
        union { bf16_t h[8]; uint4 u; } pk;
#pragma unroll
        for (int u = 0; u < 8; ++u) pk.h[u] = t[cc * 8 + u][rr];
        int dg = d0 + rr;
        size_t idx = ((size_t)(b * H + (dg >> 7)) * 128 + (dg & 127)) * S + s0 + cc * 8;
        *(uint4*)&Vt[idx] = pk.u;
    }
}

// ---------------------------------------------------------------------------
// Flash attention fwd, causal. 512 thr = 8 waves x 16 q-rows (Q-tile 128).
// Each block processes the balanced pair of q-tiles (p, 15-p): 36 K-iters each.
// K/V double-buffered via global_load_lds (pre-swizzled global source, linear
// LDS dest), 2-phase schedule: ONE barrier per K-tile, prefetch in flight.
// ---------------------------------------------------------------------------
__global__ __launch_bounds__(512) void attn_fwd(const bf16_t* __restrict__ Q,
                                                const bf16_t* __restrict__ Kk,
                                                const bf16_t* __restrict__ Vt,
                                                bf16_t* __restrict__ Ctx, int S, int H) {
    const int D = H * 128;
    const int p = blockIdx.x;   // 0..7
    const int bh = blockIdx.y;
    const int b = bh >> 4, h = bh & 15;
    const int tid = threadIdx.x;
    const int w = tid >> 6, l = tid & 63;
    const int l16 = l & 15, lg = l >> 4;

    __shared__ __align__(16) bf16_t ks[2][64 * 128];   // [key][d] chunks, XOR-swizzled
    __shared__ __align__(16) bf16_t vs[2][64 * 128];   // [d][key] chunks, XOR-swizzled
    __shared__ __align__(16) bf16_t ps[8][16 * 64];    // per-wave P, swizzled

    const float scale = 0.08838834764831845f;  // 1/sqrt(128)
    const f32x4 zero4 = {0.f, 0.f, 0.f, 0.f};

    auto stage = [&](int k0, int buf) {
#pragma unroll
        for (int j = 0; j < 2; ++j) {
            int c = tid + j * 512;
            int r = c >> 4;
            int c8 = (c & 15) ^ (r & 7);
            gload_lds16(Kk + (size_t)(b * S + k0 + r) * D + h * 128 + c8 * 8,
                        &ks[buf][(w * 64 + j * 512) * 8]);
            int dd = c >> 3;
            int k8 = (c & 7) ^ (dd & 7);
            gload_lds16(Vt + ((size_t)bh * 128 + dd) * S + k0 + k8 * 8,
                        &vs[buf][(w * 64 + j * 512) * 8]);
        }
    };

    for (int job = 0; job < 2; ++job) {
        const int qt = job ? (15 - p) : p;
        const int q0 = qt * 128;
        const int nkt = 2 * qt + 2;
        const int rmin = q0 + w * 16, rmax = rmin + 15;

        bf16x8 qf[4];
        {
            const bf16_t* qp = Q + (size_t)(b * S + rmin + l16) * D + h * 128 + lg * 8;
#pragma unroll
            for (int d4 = 0; d4 < 4; ++d4) qf[d4] = *(const bf16x8*)(qp + d4 * 32);
        }
        f32x4 ctx[8];
#pragma unroll
        for (int f = 0; f < 8; ++f) ctx[f] = zero4;
        float mrun[4] = {-INFINITY, -INFINITY, -INFINITY, -INFINITY};
        float lrun[4] = {0.f, 0.f, 0.f, 0.f};

        __syncthreads();
        stage(0, 0);
        int cur = 0;
        for (int kt = 0; kt < nkt; ++kt) {
            __syncthreads();
            if (kt + 1 < nkt) stage((kt + 1) * 64, cur ^ 1);
            const int k0 = kt * 64;
            if (k0 <= rmax) {
                f32x4 sacc[4];
#pragma unroll
                for (int kc = 0; kc < 4; ++kc) sacc[kc] = zero4;
#pragma unroll
                for (int kc = 0; kc < 4; ++kc) {
                    const int krow = kc * 16 + l16;
#pragma unroll
                    for (int d4 = 0; d4 < 4; ++d4) {
                        bf16x8 kf = *(const bf16x8*)&ks[cur][(krow * 16 + ((d4 * 4 + lg) ^ (krow & 7))) * 8];
                        sacc[kc] = __builtin_amdgcn_mfma_f32_16x16x32_bf16(qf[d4], kf, sacc[kc], 0, 0, 0);
                    }
                }
                float sv[4][4];
                const bool needmask = (k0 + 63 > rmin);
#pragma unroll
                for (int kc = 0; kc < 4; ++kc)
#pragma unroll
                    for (int r = 0; r < 4; ++r) {
                        float s = sacc[kc][r] * scale;
                        if (needmask && (k0 + kc * 16 + l16) > (rmin + lg * 4 + r)) s = -INFINITY;
                        sv[kc][r] = s;
                    }
                float alpha[4];
#pragma unroll
                for (int r = 0; r < 4; ++r) {
                    float mx = fmaxf(fmaxf(sv[0][r], sv[1][r]), fmaxf(sv[2][r], sv[3][r]));
#pragma unroll
                    for (int off = 1; off < 16; off <<= 1) mx = fmaxf(mx, __shfl_xor(mx, off));
                    float mnew = fmaxf(mrun[r], mx);
                    alpha[r] = (mrun[r] == -INFINITY) ? 0.f : __expf(mrun[r] - mnew);
                    float psum = 0.f;
#pragma unroll
                    for (int kc = 0; kc < 4; ++kc) {
                        float pe = __expf(sv[kc][r] - mnew);
                        sv[kc][r] = pe;
                        psum += pe;
                    }
#pragma unroll
                    for (int off = 1; off < 16; off <<= 1) psum += __shfl_xor(psum, off);
                    lrun[r] = lrun[r] * alpha[r] + psum;
                    mrun[r] = mnew;
                }
#pragma unroll
                for (int f = 0; f < 8; ++f) {
                    ctx[f][0] *= alpha[0]; ctx[f][1] *= alpha[1];
                    ctx[f][2] *= alpha[2]; ctx[f][3] *= alpha[3];
                }
#pragma unroll
                for (int r = 0; r < 4; ++r) {
                    int prow = lg * 4 + r;
#pragma unroll
                    for (int kc = 0; kc < 4; ++kc)
                        ps[w][prow * 64 + ((kc * 16 + l16) ^ ((prow & 7) << 3))] = (bf16_t)sv[kc][r];
                }
#pragma unroll
                for (int t = 0; t < 2; ++t) {
                    bf16x8 pa = *(const bf16x8*)&ps[w][l16 * 64 + ((t * 32 + lg * 8) ^ ((l16 & 7) << 3))];
#pragma unroll
                    for (int f = 0; f < 8; ++f) {
                        bf16x8 vb = *(const bf16x8*)&vs[cur][((f * 16 + l16) * 8 + ((t * 4 + lg) ^ (l16 & 7))) * 8];
                        ctx[f] = __builtin_amdgcn_mfma_f32_16x16x32_bf16(pa, vb, ctx[f], 0, 0, 0);
                    }
                }
            }
            cur ^= 1;
        }
        float invl[4];
#pragma unroll
        for (int r = 0; r < 4; ++r) invl[r] = 1.f / lrun[r];
#pragma unroll
        for (int f = 0; f < 8; ++f)
#pragma unroll
            for (int r = 0; r < 4; ++r) {
                int qrow = rmin + lg * 4 + r;
                Ctx[(size_t)(b * S + qrow) * D + h * 128 + f * 16 + l16] = (bf16_t)(ctx[f][r] * invl[r]);
            }
    }
}

// ---------------------------------------------------------------------------
extern "C" void kernel_launch(void* const* d_in, const int* in_sizes, int n_in,
                              void* d_out, int out_size, void* d_ws, size_t ws_size,
                              hipStream_t stream) {
    const int B = 2, S = 2048, D = 2048, H = 16;
    const int M = B * S;  // 4096
    const float* x  = (const float*)d_in[0];
    const float* wq = (const float*)d_in[1];
    const float* wk = (const float*)d_in[2];
    const float* wv = (const float*)d_in[3];
    const float* wo = (const float*)d_in[4];
    const float* bo = (const float*)d_in[5];
    float* out = (float*)d_out;

    char* ws = (char*)d_ws;
    const size_t MB = 1024 * 1024;
    if (ws_size < 128 * MB) return;
    bf16_t* xb  = (bf16_t*)(ws);
    bf16_t* wqb = (bf16_t*)(ws + 16 * MB);
    bf16_t* wkb = (bf16_t*)(ws + 24 * MB);
    bf16_t* wvb = (bf16_t*)(ws + 32 * MB);
    bf16_t* wob = (bf16_t*)(ws + 40 * MB);
    bf16_t* qb  = (bf16_t*)(ws + 48 * MB);
    bf16_t* kb  = (bf16_t*)(ws + 64 * MB);
    bf16_t* vb  = (bf16_t*)(ws + 80 * MB);
    bf16_t* vtb = (bf16_t*)(ws + 96 * MB);
    bf16_t* cxb = (bf16_t*)(ws + 112 * MB);

    cvt_f32_to_bf16<<<M * D / 8 / 256, 256, 0, stream>>>(x, xb, M * D / 8);
    cvt_f32_to_bf16<<<D * D / 8 / 256, 256, 0, stream>>>(wq, wqb, D * D / 8);
    cvt_f32_to_bf16<<<D * D / 8 / 256, 256, 0, stream>>>(wk, wkb, D * D / 8);
    cvt_f32_to_bf16<<<D * D / 8 / 256, 256, 0, stream>>>(wv, wvb, D * D / 8);
    cvt_f32_to_bf16<<<D * D / 8 / 256, 256, 0, stream>>>(wo, wob, D * D / 8);

    gemm_qkv<<<dim3(16, 16, 3), 512, 0, stream>>>(xb, wqb, wkb, wvb, qb, kb, vb, M, D, D);
    transpose_v<<<dim3(S / 64, D / 64, B), 256, 0, stream>>>(vb, vtb, S, H, B);
    attn_fwd<<<dim3(8, B * H), 512, 0, stream>>>(qb, kb, vtb, cxb, S, H);
    gemm_bias_f32<<<dim3(16, 16), 512, 0, stream>>>(cxb, wob, bo, out, M, D, D);
}

// Round 5
// 278.389 us; speedup vs baseline: 1.2814x; 1.2814x over previous
//
#include <hip/hip_runtime.h>
#include <math.h>

typedef __bf16 bf16_t;
typedef __bf16 bf16x8 __attribute__((ext_vector_type(8)));
typedef float f32x4 __attribute__((ext_vector_type(4)));

// async global->LDS, 16B per lane. Dest must be wave-uniform base; HW adds lane*16.
__device__ __forceinline__ void gload_lds16(const bf16_t* g, bf16_t* l) {
    __builtin_amdgcn_global_load_lds((const __attribute__((address_space(1))) void*)g,
                                     (__attribute__((address_space(3))) void*)l, 16, 0, 0);
}

// ---------------------------------------------------------------------------
// fused fp32 -> bf16 convert of x + 4 weights into ONE contiguous bf16 region.
// chunk layout (16B = 8 elems): x: [0, 1048576); then wq/wk/wv/wo 524288 each.
// ---------------------------------------------------------------------------
__global__ __launch_bounds__(256) void cvt_all(const float* __restrict__ x,
                                               const float* __restrict__ wq,
                                               const float* __restrict__ wk,
                                               const float* __restrict__ wv,
                                               const float* __restrict__ wo,
                                               bf16_t* __restrict__ dst) {
    int c = blockIdx.x * 256 + threadIdx.x;
    const float* src;
    size_t off;
    if (c < 1048576) { src = x; off = c; }
    else {
        int q = (c - 1048576) >> 19;  // 524288 chunks per weight
        src = (q == 0) ? wq : (q == 1) ? wk : (q == 2) ? wv : wo;
        off = (c - 1048576) & 524287;
    }
    const float4* p = (const float4*)src + off * 2;
    float4 a = p[0], b = p[1];
    union { bf16_t h[8]; uint4 u; } pk;
    pk.h[0] = (bf16_t)a.x; pk.h[1] = (bf16_t)a.y; pk.h[2] = (bf16_t)a.z; pk.h[3] = (bf16_t)a.w;
    pk.h[4] = (bf16_t)b.x; pk.h[5] = (bf16_t)b.y; pk.h[6] = (bf16_t)b.z; pk.h[7] = (bf16_t)b.w;
    ((uint4*)dst)[c] = pk.u;
}

// ---------------------------------------------------------------------------
// GEMM: C[M,N] = A[M,K] @ B[N,K]^T. 256x128 tile, BK=64, 512 thr = 8 waves
// (4M x 2N, per-wave 64x64). TRIPLE-buffered LDS (144KB, passed in from the
// kernel so template instantiations SHARE it): stage tile t+2 while computing
// tile t -> counted vmcnt(6) at tile boundary (T4), ONE barrier per K-tile.
// 2 phases per tile, minimal ds_reads (16 b128/wave/tile), setprio around
// MFMA (T5). T2 XOR swizzle (chunk ^= row&7) via pre-swizzled global source.
// MODE: 0 = bf16 C row-major; 1 = f32 C + bias; 2 = V -> Vt[B,H,128,S] fused.
// ---------------------------------------------------------------------------
template <int MODE, typename OutT>
__device__ __forceinline__ void gemm_core(bf16_t* __restrict__ AsB, bf16_t* __restrict__ BsB,
                                          const bf16_t* __restrict__ A,
                                          const bf16_t* __restrict__ Bm,
                                          const float* __restrict__ bias,
                                          OutT* __restrict__ C, bf16_t* __restrict__ Vt,
                                          int M, int N, int K, int bx, int by) {
    const int tid = threadIdx.x;
    const int w = tid >> 6, l = tid & 63;
    const int l16 = l & 15, lg = l >> 4;
    const int wr = w >> 1, wc = w & 1;  // 4 M-waves x 2 N-waves
    const int m0 = bx * 256, n0 = by * 128;
    const int lsw = l16 & 7;

    f32x4 acc[4][4] = {};

    auto stageA = [&](int k0, int buf) {  // 256x64 = 2048 chunks, 4 gloads/thread
#pragma unroll
        for (int j = 0; j < 4; ++j) {
            int c = tid + j * 512;
            int row = c >> 3;
            int kc = (c & 7) ^ (row & 7);
            gload_lds16(A + (size_t)(m0 + row) * K + k0 + kc * 8,
                        &AsB[buf * 16384 + (j * 512 + w * 64) * 8]);
        }
    };
    auto stageB = [&](int k0, int buf) {  // 128x64 = 1024 chunks, 2 gloads/thread
#pragma unroll
        for (int j = 0; j < 2; ++j) {
            int c = tid + j * 512;
            int row = c >> 3;
            int kc = (c & 7) ^ (row & 7);
            gload_lds16(Bm + (size_t)(n0 + row) * K + k0 + kc * 8,
                        &BsB[buf * 8192 + (j * 512 + w * 64) * 8]);
        }
    };

    stageA(0, 0); stageB(0, 0);      // tile 0: 6 loads
    stageA(64, 1); stageB(64, 1);    // tile 1: 6 loads
    asm volatile("s_waitcnt vmcnt(6)" ::: "memory");  // tile 0 landed
    __builtin_amdgcn_s_barrier();

    const int nt = K / 64;
    int cur = 0;
    for (int t = 0; t < nt; ++t) {
        int nxt = cur + 2; if (nxt >= 3) nxt -= 3;
        const bool pf = (t + 2 < nt);
        const int k2 = (t + 2) * 64;
        const bf16_t* Asc = &AsB[cur * 16384];
        const bf16_t* Bsc = &BsB[cur * 8192];

        // ---- phase 0: all B frags + A frags mf=0,1 ----
        bf16x8 bfr[4][2], af[2][2];
#pragma unroll
        for (int nf = 0; nf < 4; ++nf)
#pragma unroll
            for (int ks = 0; ks < 2; ++ks) {
                int brow = wc * 64 + nf * 16 + l16;
                bfr[nf][ks] = *(const bf16x8*)&Bsc[brow * 64 + (((ks << 2) | lg) ^ lsw) * 8];
            }
#pragma unroll
        for (int i = 0; i < 2; ++i)
#pragma unroll
            for (int ks = 0; ks < 2; ++ks) {
                int arow = wr * 64 + i * 16 + l16;
                af[i][ks] = *(const bf16x8*)&Asc[arow * 64 + (((ks << 2) | lg) ^ lsw) * 8];
            }
        if (pf) stageA(k2, nxt);
        asm volatile("s_waitcnt lgkmcnt(0)" ::: "memory");
        __builtin_amdgcn_sched_barrier(0);
        __builtin_amdgcn_s_setprio(1);
#pragma unroll
        for (int ks = 0; ks < 2; ++ks)
#pragma unroll
            for (int i = 0; i < 2; ++i)
#pragma unroll
                for (int nf = 0; nf < 4; ++nf)
                    acc[i][nf] = __builtin_amdgcn_mfma_f32_16x16x32_bf16(af[i][ks], bfr[nf][ks], acc[i][nf], 0, 0, 0);
        __builtin_amdgcn_s_setprio(0);

        // ---- phase 1: A frags mf=2,3 (B held in regs) ----
        bf16x8 af2[2][2];
#pragma unroll
        for (int i = 0; i < 2; ++i)
#pragma unroll
            for (int ks = 0; ks < 2; ++ks) {
                int arow = wr * 64 + (i + 2) * 16 + l16;
                af2[i][ks] = *(const bf16x8*)&Asc[arow * 64 + (((ks << 2) | lg) ^ lsw) * 8];
            }
        if (pf) stageB(k2, nxt);
        asm volatile("s_waitcnt lgkmcnt(0)" ::: "memory");
        __builtin_amdgcn_sched_barrier(0);
        __builtin_amdgcn_s_setprio(1);
#pragma unroll
        for (int ks = 0; ks < 2; ++ks)
#pragma unroll
            for (int i = 0; i < 2; ++i)
#pragma unroll
                for (int nf = 0; nf < 4; ++nf)
                    acc[i + 2][nf] = __builtin_amdgcn_mfma_f32_16x16x32_bf16(af2[i][ks], bfr[nf][ks], acc[i + 2][nf], 0, 0, 0);
        __builtin_amdgcn_s_setprio(0);

        // ---- tile boundary: counted wait (tile t+1 landed), one barrier ----
        if (pf) asm volatile("s_waitcnt vmcnt(6)" ::: "memory");
        else    asm volatile("s_waitcnt vmcnt(0)" ::: "memory");
        __builtin_amdgcn_s_barrier();
        cur = (cur + 1 == 3) ? 0 : cur + 1;
    }

    // ---- epilogue (C/D layout: row = lg*4+r, col = l16) ----
    if constexpr (MODE == 2) {
        // V: write transposed to Vt[B,H,128,S]; 4 consecutive s -> 8B store
#pragma unroll
        for (int mf = 0; mf < 4; ++mf)
#pragma unroll
            for (int nf = 0; nf < 4; ++nf) {
                int col = n0 + wc * 64 + nf * 16 + l16;   // d global
                int hh = col >> 7, dh = col & 127;
                int rowbase = m0 + wr * 64 + mf * 16 + lg * 4;
                int bb = rowbase >> 11, s = rowbase & 2047;
                union { bf16_t h[4]; ushort4 u4; } pk;
#pragma unroll
                for (int r = 0; r < 4; ++r) pk.h[r] = (bf16_t)acc[mf][nf][r];
                *(ushort4*)&Vt[(((size_t)(bb * 16 + hh)) * 128 + dh) * 2048 + s] = pk.u4;
            }
    } else {
#pragma unroll
        for (int mf = 0; mf < 4; ++mf)
#pragma unroll
            for (int nf = 0; nf < 4; ++nf) {
                int col = n0 + wc * 64 + nf * 16 + l16;
                float bv = (MODE == 1) ? bias[col] : 0.f;
#pragma unroll
                for (int r = 0; r < 4; ++r) {
                    int row = m0 + wr * 64 + mf * 16 + lg * 4 + r;
                    C[(size_t)row * N + col] = (OutT)(acc[mf][nf][r] + bv);
                }
            }
    }
}

// qkv: grid 16x16x3 = 768 blocks (3 exact CU rounds), XCD-swizzled (768%8==0).
// __shared__ declared HERE (kernel scope) so all gemm_core instantiations
// share ONE 144KB allocation (fix for round-4 LDS-doubling compile error).
__global__ __launch_bounds__(512, 2) void gemm_qkv(const bf16_t* __restrict__ A,
                                                   const bf16_t* __restrict__ W0,
                                                   const bf16_t* __restrict__ W1,
                                                   const bf16_t* __restrict__ W2,
                                                   bf16_t* __restrict__ O0, bf16_t* __restrict__ O1,
                                                   bf16_t* __restrict__ Vt, int M, int N, int K) {
    __shared__ __align__(16) bf16_t As[3 * 256 * 64];
    __shared__ __align__(16) bf16_t Bs[3 * 128 * 64];
    int flat = blockIdx.x + 16 * (blockIdx.y + 16 * blockIdx.z);
    int idx = (flat & 7) * 96 + (flat >> 3);
    int bx = idx & 15, by = (idx >> 4) & 15, bz = idx >> 8;
    if (bz == 0)      gemm_core<0, bf16_t>(As, Bs, A, W0, nullptr, O0, nullptr, M, N, K, bx, by);
    else if (bz == 1) gemm_core<0, bf16_t>(As, Bs, A, W1, nullptr, O1, nullptr, M, N, K, bx, by);
    else              gemm_core<2, bf16_t>(As, Bs, A, W2, nullptr, (bf16_t*)nullptr, Vt, M, N, K, bx, by);
}

__global__ __launch_bounds__(512, 2) void gemm_bias_f32(const bf16_t* __restrict__ A,
                                                        const bf16_t* __restrict__ Bm,
                                                        const float* __restrict__ bias,
                                                        float* __restrict__ C, int M, int N, int K) {
    __shared__ __align__(16) bf16_t As[3 * 256 * 64];
    __shared__ __align__(16) bf16_t Bs[3 * 128 * 64];
    int flat = blockIdx.x + 16 * blockIdx.y;
    int idx = (flat & 7) * 32 + (flat >> 3);   // 256 % 8 == 0
    int bx = idx & 15, by = idx >> 4;
    gemm_core<1, float>(As, Bs, A, Bm, bias, C, nullptr, M, N, K, bx, by);
}

// ---------------------------------------------------------------------------
// Flash attention fwd, causal (unchanged: validated at ~92us in rounds 2-3).
// 512 thr = 8 waves x 16 q-rows (Q-tile 128); balanced pair (p, 15-p).
// ---------------------------------------------------------------------------
__global__ __launch_bounds__(512) void attn_fwd(const bf16_t* __restrict__ Q,
                                                const bf16_t* __restrict__ Kk,
                                                const bf16_t* __restrict__ Vt,
                                                bf16_t* __restrict__ Ctx, int S, int H) {
    const int D = H * 128;
    const int p = blockIdx.x;
    const int bh = blockIdx.y;
    const int b = bh >> 4, h = bh & 15;
    const int tid = threadIdx.x;
    const int w = tid >> 6, l = tid & 63;
    const int l16 = l & 15, lg = l >> 4;

    __shared__ __align__(16) bf16_t ks[2][64 * 128];
    __shared__ __align__(16) bf16_t vs[2][64 * 128];
    __shared__ __align__(16) bf16_t ps[8][16 * 64];

    const float scale = 0.08838834764831845f;
    const f32x4 zero4 = {0.f, 0.f, 0.f, 0.f};

    auto stage = [&](int k0, int buf) {
#pragma unroll
        for (int j = 0; j < 2; ++j) {
            int c = tid + j * 512;
            int r = c >> 4;
            int c8 = (c & 15) ^ (r & 7);
            gload_lds16(Kk + (size_t)(b * S + k0 + r) * D + h * 128 + c8 * 8,
                        &ks[buf][(w * 64 + j * 512) * 8]);
            int dd = c >> 3;
            int k8 = (c & 7) ^ (dd & 7);
            gload_lds16(Vt + ((size_t)bh * 128 + dd) * S + k0 + k8 * 8,
                        &vs[buf][(w * 64 + j * 512) * 8]);
        }
    };

    for (int job = 0; job < 2; ++job) {
        const int qt = job ? (15 - p) : p;
        const int q0 = qt * 128;
        const int nkt = 2 * qt + 2;
        const int rmin = q0 + w * 16, rmax = rmin + 15;

        bf16x8 qf[4];
        {
            const bf16_t* qp = Q + (size_t)(b * S + rmin + l16) * D + h * 128 + lg * 8;
#pragma unroll
            for (int d4 = 0; d4 < 4; ++d4) qf[d4] = *(const bf16x8*)(qp + d4 * 32);
        }
        f32x4 ctx[8];
#pragma unroll
        for (int f = 0; f < 8; ++f) ctx[f] = zero4;
        float mrun[4] = {-INFINITY, -INFINITY, -INFINITY, -INFINITY};
        float lrun[4] = {0.f, 0.f, 0.f, 0.f};

        __syncthreads();
        stage(0, 0);
        int cur = 0;
        for (int kt = 0; kt < nkt; ++kt) {
            __syncthreads();
            if (kt + 1 < nkt) stage((kt + 1) * 64, cur ^ 1);
            const int k0 = kt * 64;
            if (k0 <= rmax) {
                f32x4 sacc[4];
#pragma unroll
                for (int kc = 0; kc < 4; ++kc) sacc[kc] = zero4;
#pragma unroll
                for (int kc = 0; kc < 4; ++kc) {
                    const int krow = kc * 16 + l16;
#pragma unroll
                    for (int d4 = 0; d4 < 4; ++d4) {
                        bf16x8 kf = *(const bf16x8*)&ks[cur][(krow * 16 + ((d4 * 4 + lg) ^ (krow & 7))) * 8];
                        sacc[kc] = __builtin_amdgcn_mfma_f32_16x16x32_bf16(qf[d4], kf, sacc[kc], 0, 0, 0);
                    }
                }
                float sv[4][4];
                const bool needmask = (k0 + 63 > rmin);
#pragma unroll
                for (int kc = 0; kc < 4; ++kc)
#pragma unroll
                    for (int r = 0; r < 4; ++r) {
                        float s = sacc[kc][r] * scale;
                        if (needmask && (k0 + kc * 16 + l16) > (rmin + lg * 4 + r)) s = -INFINITY;
                        sv[kc][r] = s;
                    }
                float alpha[4];
#pragma unroll
                for (int r = 0; r < 4; ++r) {
                    float mx = fmaxf(fmaxf(sv[0][r], sv[1][r]), fmaxf(sv[2][r], sv[3][r]));
#pragma unroll
                    for (int off = 1; off < 16; off <<= 1) mx = fmaxf(mx, __shfl_xor(mx, off));
                    float mnew = fmaxf(mrun[r], mx);
                    alpha[r] = (mrun[r] == -INFINITY) ? 0.f : __expf(mrun[r] - mnew);
                    float psum = 0.f;
#pragma unroll
                    for (int kc = 0; kc < 4; ++kc) {
                        float pe = __expf(sv[kc][r] - mnew);
                        sv[kc][r] = pe;
                        psum += pe;
                    }
#pragma unroll
                    for (int off = 1; off < 16; off <<= 1) psum += __shfl_xor(psum, off);
                    lrun[r] = lrun[r] * alpha[r] + psum;
                    mrun[r] = mnew;
                }
#pragma unroll
                for (int f = 0; f < 8; ++f) {
                    ctx[f][0] *= alpha[0]; ctx[f][1] *= alpha[1];
                    ctx[f][2] *= alpha[2]; ctx[f][3] *= alpha[3];
                }
#pragma unroll
                for (int r = 0; r < 4; ++r) {
                    int prow = lg * 4 + r;
#pragma unroll
                    for (int kc = 0; kc < 4; ++kc)
                        ps[w][prow * 64 + ((kc * 16 + l16) ^ ((prow & 7) << 3))] = (bf16_t)sv[kc][r];
                }
#pragma unroll
                for (int t = 0; t < 2; ++t) {
                    bf16x8 pa = *(const bf16x8*)&ps[w][l16 * 64 + ((t * 32 + lg * 8) ^ ((l16 & 7) << 3))];
#pragma unroll
                    for (int f = 0; f < 8; ++f) {
                        bf16x8 vb = *(const bf16x8*)&vs[cur][((f * 16 + l16) * 8 + ((t * 4 + lg) ^ (l16 & 7))) * 8];
                        ctx[f] = __builtin_amdgcn_mfma_f32_16x16x32_bf16(pa, vb, ctx[f], 0, 0, 0);
                    }
                }
            }
            cur ^= 1;
        }
        float invl[4];
#pragma unroll
        for (int r = 0; r < 4; ++r) invl[r] = 1.f / lrun[r];
#pragma unroll
        for (int f = 0; f < 8; ++f)
#pragma unroll
            for (int r = 0; r < 4; ++r) {
                int qrow = rmin + lg * 4 + r;
                Ctx[(size_t)(b * S + qrow) * D + h * 128 + f * 16 + l16] = (bf16_t)(ctx[f][r] * invl[r]);
            }
    }
}

// ---------------------------------------------------------------------------
extern "C" void kernel_launch(void* const* d_in, const int* in_sizes, int n_in,
                              void* d_out, int out_size, void* d_ws, size_t ws_size,
                              hipStream_t stream) {
    const int B = 2, S = 2048, D = 2048, H = 16;
    const int M = B * S;  // 4096
    const float* x  = (const float*)d_in[0];
    const float* wq = (const float*)d_in[1];
    const float* wk = (const float*)d_in[2];
    const float* wv = (const float*)d_in[3];
    const float* wo = (const float*)d_in[4];
    const float* bo = (const float*)d_in[5];
    float* out = (float*)d_out;

    char* ws = (char*)d_ws;
    const size_t MB = 1024 * 1024;
    if (ws_size < 128 * MB) return;
    bf16_t* xb  = (bf16_t*)(ws);              // cvt dst is contiguous 48MB
    bf16_t* wqb = (bf16_t*)(ws + 16 * MB);
    bf16_t* wkb = (bf16_t*)(ws + 24 * MB);
    bf16_t* wvb = (bf16_t*)(ws + 32 * MB);
    bf16_t* wob = (bf16_t*)(ws + 40 * MB);
    bf16_t* qb  = (bf16_t*)(ws + 48 * MB);
    bf16_t* kb  = (bf16_t*)(ws + 64 * MB);
    bf16_t* vtb = (bf16_t*)(ws + 80 * MB);    // V written transposed by gemm_qkv
    bf16_t* cxb = (bf16_t*)(ws + 96 * MB);

    cvt_all<<<12288, 256, 0, stream>>>(x, wq, wk, wv, wo, xb);
    gemm_qkv<<<dim3(16, 16, 3), 512, 0, stream>>>(xb, wqb, wkb, wvb, qb, kb, vtb, M, D, D);
    attn_fwd<<<dim3(8, B * H), 512, 0, stream>>>(qb, kb, vtb, cxb, S, H);
    gemm_bias_f32<<<dim3(16, 16), 512, 0, stream>>>(cxb, wob, bo, out, M, D, D);
}

// Round 6
// 270.679 us; speedup vs baseline: 1.3179x; 1.0285x over previous
//
#include <hip/hip_runtime.h>
#include <math.h>

typedef __bf16 bf16_t;
typedef __bf16 bf16x8 __attribute__((ext_vector_type(8)));
typedef float f32x4 __attribute__((ext_vector_type(4)));
typedef float f32x16 __attribute__((ext_vector_type(16)));

// async global->LDS, 16B per lane. Dest must be wave-uniform base; HW adds lane*16.
__device__ __forceinline__ void gload_lds16(const bf16_t* g, bf16_t* l) {
    __builtin_amdgcn_global_load_lds((const __attribute__((address_space(1))) void*)g,
                                     (__attribute__((address_space(3))) void*)l, 16, 0, 0);
}

// ---------------------------------------------------------------------------
// fused fp32 -> bf16 convert of x + 4 weights into ONE contiguous bf16 region.
// ---------------------------------------------------------------------------
__global__ __launch_bounds__(256) void cvt_all(const float* __restrict__ x,
                                               const float* __restrict__ wq,
                                               const float* __restrict__ wk,
                                               const float* __restrict__ wv,
                                               const float* __restrict__ wo,
                                               bf16_t* __restrict__ dst) {
    int c = blockIdx.x * 256 + threadIdx.x;
    const float* src;
    size_t off;
    if (c < 1048576) { src = x; off = c; }
    else {
        int q = (c - 1048576) >> 19;
        src = (q == 0) ? wq : (q == 1) ? wk : (q == 2) ? wv : wo;
        off = (c - 1048576) & 524287;
    }
    const float4* p = (const float4*)src + off * 2;
    float4 a = p[0], b = p[1];
    union { bf16_t h[8]; uint4 u; } pk;
    pk.h[0] = (bf16_t)a.x; pk.h[1] = (bf16_t)a.y; pk.h[2] = (bf16_t)a.z; pk.h[3] = (bf16_t)a.w;
    pk.h[4] = (bf16_t)b.x; pk.h[5] = (bf16_t)b.y; pk.h[6] = (bf16_t)b.z; pk.h[7] = (bf16_t)b.w;
    ((uint4*)dst)[c] = pk.u;
}

// ---------------------------------------------------------------------------
// GEMM (validated round 5): 256x128 tile, BK=64, 8 waves, triple-buffered LDS,
// counted vmcnt(6), one barrier per K-tile, T2 swizzle, setprio.
// ---------------------------------------------------------------------------
template <int MODE, typename OutT>
__device__ __forceinline__ void gemm_core(bf16_t* __restrict__ AsB, bf16_t* __restrict__ BsB,
                                          const bf16_t* __restrict__ A,
                                          const bf16_t* __restrict__ Bm,
                                          const float* __restrict__ bias,
                                          OutT* __restrict__ C, bf16_t* __restrict__ Vt,
                                          int M, int N, int K, int bx, int by) {
    const int tid = threadIdx.x;
    const int w = tid >> 6, l = tid & 63;
    const int l16 = l & 15, lg = l >> 4;
    const int wr = w >> 1, wc = w & 1;
    const int m0 = bx * 256, n0 = by * 128;
    const int lsw = l16 & 7;

    f32x4 acc[4][4] = {};

    auto stageA = [&](int k0, int buf) {
#pragma unroll
        for (int j = 0; j < 4; ++j) {
            int c = tid + j * 512;
            int row = c >> 3;
            int kc = (c & 7) ^ (row & 7);
            gload_lds16(A + (size_t)(m0 + row) * K + k0 + kc * 8,
                        &AsB[buf * 16384 + (j * 512 + w * 64) * 8]);
        }
    };
    auto stageB = [&](int k0, int buf) {
#pragma unroll
        for (int j = 0; j < 2; ++j) {
            int c = tid + j * 512;
            int row = c >> 3;
            int kc = (c & 7) ^ (row & 7);
            gload_lds16(Bm + (size_t)(n0 + row) * K + k0 + kc * 8,
                        &BsB[buf * 8192 + (j * 512 + w * 64) * 8]);
        }
    };

    stageA(0, 0); stageB(0, 0);
    stageA(64, 1); stageB(64, 1);
    asm volatile("s_waitcnt vmcnt(6)" ::: "memory");
    __builtin_amdgcn_s_barrier();

    const int nt = K / 64;
    int cur = 0;
    for (int t = 0; t < nt; ++t) {
        int nxt = cur + 2; if (nxt >= 3) nxt -= 3;
        const bool pf = (t + 2 < nt);
        const int k2 = (t + 2) * 64;
        const bf16_t* Asc = &AsB[cur * 16384];
        const bf16_t* Bsc = &BsB[cur * 8192];

        bf16x8 bfr[4][2], af[2][2];
#pragma unroll
        for (int nf = 0; nf < 4; ++nf)
#pragma unroll
            for (int ks = 0; ks < 2; ++ks) {
                int brow = wc * 64 + nf * 16 + l16;
                bfr[nf][ks] = *(const bf16x8*)&Bsc[brow * 64 + (((ks << 2) | lg) ^ lsw) * 8];
            }
#pragma unroll
        for (int i = 0; i < 2; ++i)
#pragma unroll
            for (int ks = 0; ks < 2; ++ks) {
                int arow = wr * 64 + i * 16 + l16;
                af[i][ks] = *(const bf16x8*)&Asc[arow * 64 + (((ks << 2) | lg) ^ lsw) * 8];
            }
        if (pf) stageA(k2, nxt);
        asm volatile("s_waitcnt lgkmcnt(0)" ::: "memory");
        __builtin_amdgcn_sched_barrier(0);
        __builtin_amdgcn_s_setprio(1);
#pragma unroll
        for (int ks = 0; ks < 2; ++ks)
#pragma unroll
            for (int i = 0; i < 2; ++i)
#pragma unroll
                for (int nf = 0; nf < 4; ++nf)
                    acc[i][nf] = __builtin_amdgcn_mfma_f32_16x16x32_bf16(af[i][ks], bfr[nf][ks], acc[i][nf], 0, 0, 0);
        __builtin_amdgcn_s_setprio(0);

        bf16x8 af2[2][2];
#pragma unroll
        for (int i = 0; i < 2; ++i)
#pragma unroll
            for (int ks = 0; ks < 2; ++ks) {
                int arow = wr * 64 + (i + 2) * 16 + l16;
                af2[i][ks] = *(const bf16x8*)&Asc[arow * 64 + (((ks << 2) | lg) ^ lsw) * 8];
            }
        if (pf) stageB(k2, nxt);
        asm volatile("s_waitcnt lgkmcnt(0)" ::: "memory");
        __builtin_amdgcn_sched_barrier(0);
        __builtin_amdgcn_s_setprio(1);
#pragma unroll
        for (int ks = 0; ks < 2; ++ks)
#pragma unroll
            for (int i = 0; i < 2; ++i)
#pragma unroll
                for (int nf = 0; nf < 4; ++nf)
                    acc[i + 2][nf] = __builtin_amdgcn_mfma_f32_16x16x32_bf16(af2[i][ks], bfr[nf][ks], acc[i + 2][nf], 0, 0, 0);
        __builtin_amdgcn_s_setprio(0);

        if (pf) asm volatile("s_waitcnt vmcnt(6)" ::: "memory");
        else    asm volatile("s_waitcnt vmcnt(0)" ::: "memory");
        __builtin_amdgcn_s_barrier();
        cur = (cur + 1 == 3) ? 0 : cur + 1;
    }

    if constexpr (MODE == 2) {
#pragma unroll
        for (int mf = 0; mf < 4; ++mf)
#pragma unroll
            for (int nf = 0; nf < 4; ++nf) {
                int col = n0 + wc * 64 + nf * 16 + l16;
                int hh = col >> 7, dh = col & 127;
                int rowbase = m0 + wr * 64 + mf * 16 + lg * 4;
                int bb = rowbase >> 11, s = rowbase & 2047;
                union { bf16_t h[4]; ushort4 u4; } pk;
#pragma unroll
                for (int r = 0; r < 4; ++r) pk.h[r] = (bf16_t)acc[mf][nf][r];
                *(ushort4*)&Vt[(((size_t)(bb * 16 + hh)) * 128 + dh) * 2048 + s] = pk.u4;
            }
    } else {
#pragma unroll
        for (int mf = 0; mf < 4; ++mf)
#pragma unroll
            for (int nf = 0; nf < 4; ++nf) {
                int col = n0 + wc * 64 + nf * 16 + l16;
                float bv = (MODE == 1) ? bias[col] : 0.f;
#pragma unroll
                for (int r = 0; r < 4; ++r) {
                    int row = m0 + wr * 64 + mf * 16 + lg * 4 + r;
                    C[(size_t)row * N + col] = (OutT)(acc[mf][nf][r] + bv);
                }
            }
    }
}

__global__ __launch_bounds__(512, 2) void gemm_qkv(const bf16_t* __restrict__ A,
                                                   const bf16_t* __restrict__ W0,
                                                   const bf16_t* __restrict__ W1,
                                                   const bf16_t* __restrict__ W2,
                                                   bf16_t* __restrict__ O0, bf16_t* __restrict__ O1,
                                                   bf16_t* __restrict__ Vt, int M, int N, int K) {
    __shared__ __align__(16) bf16_t As[3 * 256 * 64];
    __shared__ __align__(16) bf16_t Bs[3 * 128 * 64];
    int flat = blockIdx.x + 16 * (blockIdx.y + 16 * blockIdx.z);
    int idx = (flat & 7) * 96 + (flat >> 3);
    int bx = idx & 15, by = (idx >> 4) & 15, bz = idx >> 8;
    if (bz == 0)      gemm_core<0, bf16_t>(As, Bs, A, W0, nullptr, O0, nullptr, M, N, K, bx, by);
    else if (bz == 1) gemm_core<0, bf16_t>(As, Bs, A, W1, nullptr, O1, nullptr, M, N, K, bx, by);
    else              gemm_core<2, bf16_t>(As, Bs, A, W2, nullptr, (bf16_t*)nullptr, Vt, M, N, K, bx, by);
}

__global__ __launch_bounds__(512, 2) void gemm_bias_f32(const bf16_t* __restrict__ A,
                                                        const bf16_t* __restrict__ Bm,
                                                        const float* __restrict__ bias,
                                                        float* __restrict__ C, int M, int N, int K) {
    __shared__ __align__(16) bf16_t As[3 * 256 * 64];
    __shared__ __align__(16) bf16_t Bs[3 * 128 * 64];
    int flat = blockIdx.x + 16 * blockIdx.y;
    int idx = (flat & 7) * 32 + (flat >> 3);
    int bx = idx & 15, by = idx >> 4;
    gemm_core<1, float>(As, Bs, A, Bm, bias, C, nullptr, M, N, K, bx, by);
}

// ---------------------------------------------------------------------------
// Flash attention fwd, causal — swapped-operand 32x32 structure (m214-style).
// 512 thr = 8 waves x 32 q-rows (block = 256 rows). Per K-tile (64 keys):
//   S^T = mfma_32x32x16(K_frag, Q_frag): lane owns q = lane&31, 32 S-values.
//   softmax fully in-register (tree + 1 shfl_xor(32)); defer-max (T13).
//   P^T frag built via bf16 pack + 2 shfl_xor(32) per 16-key step (T12-ish).
//   ctx^T = mfma(V^T_frag, P^T_frag): O stays lane-local, scalar rescale.
// K [64][128] and V^T [128][64] LDS tiles, double-buffered, XOR-swizzled,
// staged by pre-swizzled-source global_load_lds.
// ---------------------------------------------------------------------------
__global__ __launch_bounds__(512, 2) void attn_fwd(const bf16_t* __restrict__ Q,
                                                   const bf16_t* __restrict__ Kk,
                                                   const bf16_t* __restrict__ Vt,
                                                   bf16_t* __restrict__ Ctx, int S, int H) {
    const int D = H * 128;
    const int bh = blockIdx.x;          // 32: same-bh blocks share K/V in L2/XCD
    const int qb = blockIdx.y;          // 8
    const int b = bh >> 4, h = bh & 15;
    const int tid = threadIdx.x;
    const int w = tid >> 6, l = tid & 63;
    const int l32 = l & 31, hi = l >> 5;
    const int q0w = qb * 256 + w * 32;
    const int qrow = q0w + l32;

    __shared__ __align__(16) bf16_t ks[2][64 * 128];   // [key][d] chunks, swizzled
    __shared__ __align__(16) bf16_t vs[2][128 * 64];   // [d][key] chunks, swizzled

    // Q frags (B-operand): col=q=lane&31, k(d) = dstep*16 + hi*8 + j
    bf16x8 qf[8];
    {
        const bf16_t* qp = Q + (size_t)(b * S + qrow) * D + h * 128 + hi * 8;
#pragma unroll
        for (int d = 0; d < 8; ++d) qf[d] = *(const bf16x8*)(qp + d * 16);
    }

    f32x16 ctx[4] = {};          // ctx^T[d-block][q=lane&31]
    float mrun = -INFINITY, lrun = 0.f;
    const float Cs = 0.08838834764831845f * 1.4426950408889634f;  // scale*log2(e)

    auto stage = [&](int k0, int buf) {
#pragma unroll
        for (int j = 0; j < 2; ++j) {
            int c = tid + j * 512;
            int r = c >> 4;
            int c16 = (c & 15) ^ (r & 7);
            gload_lds16(Kk + (size_t)(b * S + k0 + r) * D + h * 128 + c16 * 8,
                        &ks[buf][(j * 512 + w * 64) * 8]);
            int dd = c >> 3;
            int k8 = (c & 7) ^ (dd & 7);
            gload_lds16(Vt + ((size_t)bh * 128 + dd) * S + k0 + k8 * 8,
                        &vs[buf][(j * 512 + w * 64) * 8]);
        }
    };

    stage(0, 0);
    const int nkt = 4 * qb + 4;
    int cur = 0;
    for (int kt = 0; kt < nkt; ++kt) {
        __syncthreads();
        if (kt + 1 < nkt) stage((kt + 1) * 64, cur ^ 1);
        const int k0 = kt * 64;
        if (k0 <= q0w + 31) {  // wave-uniform skip of fully-masked tiles
            // ---- S^T = K @ Q^T : sacc[t2] covers keys 32*t2..+31 ----
            f32x16 sacc[2] = {};
#pragma unroll
            for (int d = 0; d < 8; ++d) {
#pragma unroll
                for (int t2 = 0; t2 < 2; ++t2) {
                    int row = t2 * 32 + l32;
                    int c16 = (2 * d + hi) ^ (row & 7);
                    bf16x8 kf = *(const bf16x8*)&ks[cur][(row * 16 + c16) * 8];
                    sacc[t2] = __builtin_amdgcn_mfma_f32_32x32x16_bf16(kf, qf[d], sacc[t2], 0, 0, 0);
                }
            }
            // ---- scale (exp2-domain) + causal mask; lane's q-row = qrow ----
            const bool diag = (k0 + 63 > q0w);  // wave-uniform
#pragma unroll
            for (int t2 = 0; t2 < 2; ++t2)
#pragma unroll
                for (int c = 0; c < 16; ++c) {
                    float s = sacc[t2][c] * Cs;
                    if (diag) {
                        int key = k0 + 32 * t2 + (c & 3) + 8 * (c >> 2) + 4 * hi;
                        if (key > qrow) s = -INFINITY;
                    }
                    sacc[t2][c] = s;
                }
            // ---- row max: in-lane tree + partner exchange ----
            float tm[16];
#pragma unroll
            for (int c = 0; c < 16; ++c) tm[c] = fmaxf(sacc[0][c], sacc[1][c]);
#pragma unroll
            for (int sft = 8; sft; sft >>= 1)
#pragma unroll
                for (int c = 0; c < 8; ++c)
                    if (c < sft) tm[c] = fmaxf(tm[c], tm[c + sft]);
            float pmax = fmaxf(tm[0], __shfl_xor(tm[0], 32));
            // ---- defer-max rescale (T13, THR=8 in exp2 domain) ----
            if (!__all(pmax <= mrun + 8.f)) {
                float mnew = fmaxf(mrun, pmax);
                float alpha = exp2f(mrun - mnew);   // mrun=-inf -> 0
                lrun *= alpha;
#pragma unroll
                for (int dblk = 0; dblk < 4; ++dblk)
#pragma unroll
                    for (int c = 0; c < 16; ++c) ctx[dblk][c] *= alpha;
                mrun = mnew;
            }
            // ---- exp + row sum ----
#pragma unroll
            for (int t2 = 0; t2 < 2; ++t2)
#pragma unroll
                for (int c = 0; c < 16; ++c) sacc[t2][c] = exp2f(sacc[t2][c] - mrun);
            float ts[16];
#pragma unroll
            for (int c = 0; c < 16; ++c) ts[c] = sacc[0][c] + sacc[1][c];
#pragma unroll
            for (int sft = 8; sft; sft >>= 1)
#pragma unroll
                for (int c = 0; c < 8; ++c)
                    if (c < sft) ts[c] += ts[c + sft];
            lrun += ts[0] + __shfl_xor(ts[0], 32);
            // ---- P^T frags: pack bf16 + partner swap (keys hi*8+j+16*ks) ----
            bf16x8 pa[4];
#pragma unroll
            for (int ksx = 0; ksx < 4; ++ksx) {
                const int t2 = ksx >> 1, cb = (ksx & 1) * 8;
                union { bf16_t hh[4]; unsigned u[2]; } Wlo, Whi;
#pragma unroll
                for (int i = 0; i < 4; ++i) {
                    Wlo.hh[i] = (bf16_t)sacc[t2][cb + i];
                    Whi.hh[i] = (bf16_t)sacc[t2][cb + 4 + i];
                }
                unsigned s0 = hi ? Wlo.u[0] : Whi.u[0];
                unsigned s1 = hi ? Wlo.u[1] : Whi.u[1];
                unsigned r0 = __shfl_xor(s0, 32);
                unsigned r1 = __shfl_xor(s1, 32);
                union { unsigned u[4]; bf16x8 v; } F;
                if (hi == 0) { F.u[0] = Wlo.u[0]; F.u[1] = Wlo.u[1]; F.u[2] = r0; F.u[3] = r1; }
                else         { F.u[0] = r0; F.u[1] = r1; F.u[2] = Whi.u[0]; F.u[3] = Whi.u[1]; }
                pa[ksx] = F.v;
            }
            // ---- ctx^T += V^T @ P^T ----
#pragma unroll
            for (int ksx = 0; ksx < 4; ++ksx)
#pragma unroll
                for (int dblk = 0; dblk < 4; ++dblk) {
                    int dd = dblk * 32 + l32;
                    int k8 = (2 * ksx + hi) ^ (dd & 7);
                    bf16x8 vf = *(const bf16x8*)&vs[cur][(dd * 8 + k8) * 8];
                    ctx[dblk] = __builtin_amdgcn_mfma_f32_32x32x16_bf16(vf, pa[ksx], ctx[dblk], 0, 0, 0);
                }
        }
        cur ^= 1;
    }
    // ---- epilogue: lane q=qrow; d = 32*dblk + 8*cg + 4*hi + i ----
    float invl = 1.f / lrun;
    bf16_t* op = Ctx + (size_t)(b * S + qrow) * D + h * 128;
#pragma unroll
    for (int dblk = 0; dblk < 4; ++dblk)
#pragma unroll
        for (int cg = 0; cg < 4; ++cg) {
            union { bf16_t hh[4]; ushort4 u4; } pk;
#pragma unroll
            for (int i = 0; i < 4; ++i) pk.hh[i] = (bf16_t)(ctx[dblk][cg * 4 + i] * invl);
            *(ushort4*)&op[dblk * 32 + cg * 8 + hi * 4] = pk.u4;
        }
}

// ---------------------------------------------------------------------------
extern "C" void kernel_launch(void* const* d_in, const int* in_sizes, int n_in,
                              void* d_out, int out_size, void* d_ws, size_t ws_size,
                              hipStream_t stream) {
    const int B = 2, S = 2048, D = 2048, H = 16;
    const int M = B * S;
    const float* x  = (const float*)d_in[0];
    const float* wq = (const float*)d_in[1];
    const float* wk = (const float*)d_in[2];
    const float* wv = (const float*)d_in[3];
    const float* wo = (const float*)d_in[4];
    const float* bo = (const float*)d_in[5];
    float* out = (float*)d_out;

    char* ws = (char*)d_ws;
    const size_t MB = 1024 * 1024;
    if (ws_size < 128 * MB) return;
    bf16_t* xb  = (bf16_t*)(ws);
    bf16_t* wqb = (bf16_t*)(ws + 16 * MB);
    bf16_t* wkb = (bf16_t*)(ws + 24 * MB);
    bf16_t* wvb = (bf16_t*)(ws + 32 * MB);
    bf16_t* wob = (bf16_t*)(ws + 40 * MB);
    bf16_t* qb  = (bf16_t*)(ws + 48 * MB);
    bf16_t* kb  = (bf16_t*)(ws + 64 * MB);
    bf16_t* vtb = (bf16_t*)(ws + 80 * MB);
    bf16_t* cxb = (bf16_t*)(ws + 96 * MB);

    cvt_all<<<12288, 256, 0, stream>>>(x, wq, wk, wv, wo, xb);
    gemm_qkv<<<dim3(16, 16, 3), 512, 0, stream>>>(xb, wqb, wkb, wvb, qb, kb, vtb, M, D, D);
    attn_fwd<<<dim3(32, 8), 512, 0, stream>>>(qb, kb, vtb, cxb, S, H);
    gemm_bias_f32<<<dim3(16, 16), 512, 0, stream>>>(cxb, wob, bo, out, M, D, D);
}